// Round 9
// baseline (32.854 us; speedup 1.0000x reference)
//
#include <hip/hip_runtime.h>
#include <math.h>

#define TPB    256
#define NPROD  32         // producer blocks; block NPROD is the consumer
#define PERCAP 256        // candidate slots per producer region in ws
#define CAPS   2048       // consumer LDS candidate capacity
#define BMW    256        // per-producer bitmap words (8192 bits)
#define NW     (TPB / 64)

typedef unsigned long long ull;

__device__ __forceinline__ ull umin64(ull a, ull b) { return a < b ? a : b; }
__device__ __forceinline__ ull umax64(ull a, ull b) { return a > b ? a : b; }

// Branchless order-statistic merge of two ascending 5-lists of 64-bit keys.
// Key = (dist_bits << 32) | p. obs_idx is sorted, so ordering/tie-break by
// cell index p is a monotone bijection of the reference's obs-enumeration
// index j -> exact jax.lax.top_k semantics (lower index wins ties).
__device__ __forceinline__ void merge5u(ull& a0, ull& a1, ull& a2, ull& a3, ull& a4,
                                        ull b0, ull b1, ull b2, ull b3, ull b4) {
    ull m0 = umin64(a0, b0);
    ull m1 = umin64(umin64(a1, b1), umax64(a0, b0));
    ull m2 = umin64(umin64(a2, b2), umin64(umax64(a0, b1), umax64(a1, b0)));
    ull m3 = umin64(umin64(a3, b3),
                    umin64(umin64(umax64(a0, b2), umax64(a1, b1)), umax64(a2, b0)));
    ull m4 = umin64(umin64(a4, b4),
                    umin64(umin64(umax64(a0, b3), umax64(a1, b2)),
                           umin64(umax64(a2, b1), umax64(a3, b0))));
    a0 = m0; a1 = m1; a2 = m2; a3 = m3; a4 = m4;
}

__device__ __forceinline__ void insert5u(ull key, ull& k0, ull& k1, ull& k2, ull& k3, ull& k4) {
    if (key < k4) {
        k4 = key;
        ull t;
        if (k4 < k3) { t = k3; k3 = k4; k4 = t; }
        if (k3 < k2) { t = k2; k2 = k3; k3 = t; }
        if (k2 < k1) { t = k1; k1 = k2; k2 = t; }
        if (k1 < k0) { t = k0; k0 = k1; k1 = t; }
    }
}

#define BFLYU(kk0,kk1,kk2,kk3,kk4,WIDTH)                            \
    for (int mask_ = 1; mask_ < (WIDTH); mask_ <<= 1) {             \
        ull b0_ = __shfl_xor(kk0, mask_, 64);                       \
        ull b1_ = __shfl_xor(kk1, mask_, 64);                       \
        ull b2_ = __shfl_xor(kk2, mask_, 64);                       \
        ull b3_ = __shfl_xor(kk3, mask_, 64);                       \
        ull b4_ = __shfl_xor(kk4, mask_, 64);                       \
        merge5u(kk0, kk1, kk2, kk3, kk4, b0_, b1_, b2_, b3_, b4_);  \
    }

// ---------------------------------------------------------------------------
// Single dispatch. Blocks 0..NPROD-1 (producers) = R4's prep: observed-only
// copy of a disjoint slice + slice threshold + ballot-compacted candidates
// into per-block ws regions; then fence + release-store flag. Block NPROD
// (consumer) spin-waits on all flags (agent scope), reads counts/candidates
// via agent-scope ATOMIC loads (defeats cross-XCD stale L2 — R7's lesson),
// solves the 3 exact iterations, writes the missing bytes. Producer writes
// (observed bytes) and consumer writes (missing bytes) are byte-disjoint.
// Flag protocol is poison/replay-safe: wait-for-1, reset-to-0 after consume.
// Threshold proof (v0=0): r0 = global 5th-smallest observed |x| <= r_loc.
// iter1 picks |x|<=r0 -> |v1|<=r0; d5(v1)<=2r0 -> iter2 picks |x|<=3r0 ->
// |v2|<=3r0; d5(v2)<=4r0 -> iter3 picks |x|<=7r0 < 8r_loc. Keeping
// x^2 <= 64*r_loc^2 is a strict superset of everything selectable.
// ---------------------------------------------------------------------------
__global__ void __launch_bounds__(TPB) knn_fused_kernel(
    const float* __restrict__ X, const int* __restrict__ miss_idx,
    const int* __restrict__ obs_idx, float* __restrict__ out,
    int* __restrict__ flags, int* __restrict__ counts, ull* __restrict__ cand,
    int n, int n_obs, int n_miss, int per, int percap)
{
    const int tid  = threadIdx.x;
    const int b    = blockIdx.x;
    const int wid  = tid >> 6;
    const int lane = tid & 63;
    const int n4   = n >> 2;

    if (b < NPROD) {
        // ================= producer =================
        __shared__ unsigned bm[BMW];
        __shared__ ull      sku[NW * 5];
        __shared__ float    thr_sh;
        __shared__ int      wcnt[NW];

        const int epb4 = (n4 + NPROD - 1) / NPROD;
        const int g0   = b * epb4;
        const int g1   = min(n4, g0 + epb4);
        const int pbeg = g0 << 2;
        const int pend = (b == NPROD - 1) ? n : (g1 << 2);
        const int bmwu = (pend > pbeg) ? ((pend - pbeg + 31) >> 5) : 0;

        for (int w = tid; w < bmwu; w += TPB) bm[w] = 0u;
        __syncthreads();
        for (int e = tid; e < n_miss; e += TPB) {           // coalesced scan; ~102 hit
            int p = miss_idx[e];
            if (p >= pbeg && p < pend)
                atomicOr(&bm[(p - pbeg) >> 5], 1u << ((p - pbeg) & 31));
        }
        __syncthreads();

        // observed-only copy (missing bytes are written only by the consumer)
        for (int g = g0 + tid; g < g1; g += TPB) {
            float4 xx = reinterpret_cast<const float4*>(X)[g];
            int off = (g << 2) - pbeg;
            unsigned bits = (bm[off >> 5] >> (off & 31)) & 0xFu;
            if (bits == 0u) {
                reinterpret_cast<float4*>(out)[g] = xx;
            } else {
                float c4[4] = {xx.x, xx.y, xx.z, xx.w};
#pragma unroll
                for (int c = 0; c < 4; ++c)
                    if (!(bits & (1u << c))) out[(g << 2) + c] = c4[c];
            }
        }
        if (b == NPROD - 1) {                               // scalar tail (empty here)
            for (int p = (n4 << 2) + tid; p < n; p += TPB) {
                int off = p - pbeg;
                if (!((bm[off >> 5] >> (off & 31)) & 1u)) out[p] = X[p];
            }
        }

        // ---- slice gather + top-5 by (x^2, p) -> threshold (R4 verbatim) ----
        const int j0 = b * per;
        const int j1 = min(j0 + per, n_obs);
        int   pi[4]; float xv[4];
#pragma unroll
        for (int u = 0; u < 4; ++u) {
            int j = j0 + tid + u * TPB;
            pi[u] = (j < j1) ? obs_idx[j] : 0;
        }
#pragma unroll
        for (int u = 0; u < 4; ++u) xv[u] = X[pi[u]];

        ull k0 = ~0ull, k1 = ~0ull, k2 = ~0ull, k3 = ~0ull, k4 = ~0ull;
#pragma unroll
        for (int u = 0; u < 4; ++u) {
            int j = j0 + tid + u * TPB;
            if (j < j1) {
                float x = xv[u];
                insert5u(((ull)__float_as_uint(x * x) << 32) | (unsigned)pi[u],
                         k0, k1, k2, k3, k4);
            }
        }
        BFLYU(k0, k1, k2, k3, k4, 64)
        if (lane == 0) {
            sku[wid * 5 + 0] = k0; sku[wid * 5 + 1] = k1; sku[wid * 5 + 2] = k2;
            sku[wid * 5 + 3] = k3; sku[wid * 5 + 4] = k4;
        }
        __syncthreads();
        if (wid == 0) {
            ull g0k = ~0ull, g1k = ~0ull, g2k = ~0ull, g3k = ~0ull, g4k = ~0ull;
            if (lane < NW) {
                g0k = sku[lane * 5 + 0]; g1k = sku[lane * 5 + 1]; g2k = sku[lane * 5 + 2];
                g3k = sku[lane * 5 + 3]; g4k = sku[lane * 5 + 4];
            }
            BFLYU(g0k, g1k, g2k, g3k, g4k, NW)
            if (lane == 0) {
                float d5 = __uint_as_float((unsigned)(g4k >> 32));  // r_loc^2
                thr_sh = 64.0f * d5;    // (8*r_loc)^2; NaN -> keeps none -> fallback
            }
        }
        __syncthreads();
        const float thr = thr_sh;

        // ---- order-preserving 4-round ballot compaction (R4 verbatim) ----
        const ull lmlt = (1ull << lane) - 1ull;
        int base = 0;
#pragma unroll
        for (int u = 0; u < 4; ++u) {
            int  j    = j0 + tid + u * TPB;
            bool keep = (j < j1) && (xv[u] * xv[u] <= thr);
            ull  mask = __ballot(keep);
            if (lane == 0) wcnt[wid] = (int)__popcll(mask);
            __syncthreads();
            int wbase = 0, utot = 0;
#pragma unroll
            for (int w = 0; w < NW; ++w) {
                if (w == wid) wbase = utot;
                utot += wcnt[w];
            }
            int pos = base + wbase + (int)__popcll(mask & lmlt);
            if (keep && pos < percap)
                cand[b * percap + pos] =
                    ((ull)(unsigned)pi[u] << 32) | (ull)__float_as_uint(xv[u]);
            base += utot;
            __syncthreads();
        }
        if (tid == 0) counts[b] = base;     // may exceed percap -> consumer falls back
        __threadfence();                    // device-scope release of out/cand/counts
        __syncthreads();
        if (tid == 0)
            __hip_atomic_store(&flags[b], 1, __ATOMIC_RELEASE, __HIP_MEMORY_SCOPE_AGENT);
        return;
    }

    // ================= consumer (b == NPROD) =================
    __shared__ uint2 cs[CAPS];
    __shared__ int   carr[NPROD];
    __shared__ int   bases[NPROD + 1];
    __shared__ int   bad_sh;
    __shared__ float v_sh;
    __shared__ ull   sku2[NW * 5];
    __shared__ ull   wk[5];
    __shared__ float vals[5];

    // spin until every producer released its flag (agent scope)
    if (wid == 0 && lane < NPROD) {
        while (__hip_atomic_load(&flags[lane], __ATOMIC_ACQUIRE,
                                 __HIP_MEMORY_SCOPE_AGENT) != 1)
            __builtin_amdgcn_s_sleep(1);
        carr[lane] = __hip_atomic_load(&counts[lane], __ATOMIC_RELAXED,
                                       __HIP_MEMORY_SCOPE_AGENT);
    }
    __syncthreads();
    __threadfence();
    if (tid == 0) {
        int C = 0, bad = 0;
        for (int r = 0; r < NPROD; ++r) {
            bases[r] = C;
            int c = carr[r];
            if (c < 0 || c > percap) bad = 1;
            C += c;
        }
        bases[NPROD] = C;
        bad_sh = bad || (C < 5) || (C > CAPS) || (percap <= 0);
    }
    __syncthreads();
    const int  C    = bases[NPROD];
    const bool fast = !bad_sh;

    // stage candidates via agent-scope atomic loads (bypass stale caches)
    if (fast) {
        const int r   = tid >> 3;          // 8 threads per region
        const int off = tid & 7;
        const int bb  = bases[r];
        const int cr  = carr[r];
        for (int e = off; e < cr; e += 8) {
            ull raw = __hip_atomic_load(&cand[r * percap + e], __ATOMIC_RELAXED,
                                        __HIP_MEMORY_SCOPE_AGENT);
            cs[bb + e] = make_uint2((unsigned)raw, (unsigned)(raw >> 32)); // (xbits, p)
        }
    }
    __syncthreads();
    // reset flags for the next replay (ws data fully consumed)
    if (tid < NPROD)
        __hip_atomic_store(&flags[tid], 0, __ATOMIC_RELAXED, __HIP_MEMORY_SCOPE_AGENT);

    float v = 0.0f;   // reference inits missing entries to 0
    if (fast) {
        // register-cached candidates (static-indexed, C <= 2048 = 8*TPB)
        float cx[8]; unsigned cp[8];
#pragma unroll
        for (int k = 0; k < 8; ++k) {
            int e = tid + k * TPB;
            if (e < C) { uint2 ce = cs[e]; cx[k] = __uint_as_float(ce.x); cp[k] = ce.y; }
            else       { cx[k] = 0.0f; cp[k] = 0xFFFFFFFFu; }
        }
        for (int it = 0; it < 3; ++it) {
            ull q0 = ~0ull, q1 = ~0ull, q2 = ~0ull, q3 = ~0ull, q4 = ~0ull;
#pragma unroll
            for (int k = 0; k < 8; ++k) {
                int e = tid + k * TPB;
                if (e < C) {
                    float df = v - cx[k];
                    insert5u(((ull)__float_as_uint(df * df) << 32) | (ull)cp[k],
                             q0, q1, q2, q3, q4);
                }
            }
            BFLYU(q0, q1, q2, q3, q4, 64)
            if (lane == 0) {
                sku2[wid * 5 + 0] = q0; sku2[wid * 5 + 1] = q1; sku2[wid * 5 + 2] = q2;
                sku2[wid * 5 + 3] = q3; sku2[wid * 5 + 4] = q4;
            }
            __syncthreads();
            if (wid == 0) {
                ull g0 = ~0ull, g1 = ~0ull, g2 = ~0ull, g3 = ~0ull, g4 = ~0ull;
                if (lane < NW) {
                    g0 = sku2[lane * 5 + 0]; g1 = sku2[lane * 5 + 1]; g2 = sku2[lane * 5 + 2];
                    g3 = sku2[lane * 5 + 3]; g4 = sku2[lane * 5 + 4];
                }
                BFLYU(g0, g1, g2, g3, g4, NW)
                if (lane == 0) { wk[0] = g0; wk[1] = g1; wk[2] = g2; wk[3] = g3; wk[4] = g4; }
            }
            __syncthreads();
            unsigned w0 = (unsigned)wk[0], w1 = (unsigned)wk[1], w2 = (unsigned)wk[2],
                     w3 = (unsigned)wk[3], w4 = (unsigned)wk[4];
#pragma unroll
            for (int k = 0; k < 8; ++k) {       // unique p -> exactly one writer each
                if (cp[k] == w0) vals[0] = cx[k];
                if (cp[k] == w1) vals[1] = cx[k];
                if (cp[k] == w2) vals[2] = cx[k];
                if (cp[k] == w3) vals[3] = cx[k];
                if (cp[k] == w4) vals[4] = cx[k];
            }
            __syncthreads();
            if (tid == 0) {
                // ascending (dist, p) order == reference's sum order exactly
                float s = vals[0]; s += vals[1]; s += vals[2]; s += vals[3]; s += vals[4];
                v_sh = s * 0.2f;
            }
            __syncthreads();
            v = v_sh;
            __syncthreads();
        }
    } else {
        // exact full-scan fallback over read-only inputs (no staleness possible)
        for (int it = 0; it < 3; ++it) {
            ull q0 = ~0ull, q1 = ~0ull, q2 = ~0ull, q3 = ~0ull, q4 = ~0ull;
            for (int e = tid; e < n_obs; e += TPB) {
                int   p  = obs_idx[e];
                float df = v - X[p];
                insert5u(((ull)__float_as_uint(df * df) << 32) | (unsigned)p,
                         q0, q1, q2, q3, q4);
            }
            BFLYU(q0, q1, q2, q3, q4, 64)
            if (lane == 0) {
                sku2[wid * 5 + 0] = q0; sku2[wid * 5 + 1] = q1; sku2[wid * 5 + 2] = q2;
                sku2[wid * 5 + 3] = q3; sku2[wid * 5 + 4] = q4;
            }
            __syncthreads();
            if (wid == 0) {
                ull g0 = ~0ull, g1 = ~0ull, g2 = ~0ull, g3 = ~0ull, g4 = ~0ull;
                if (lane < NW) {
                    g0 = sku2[lane * 5 + 0]; g1 = sku2[lane * 5 + 1]; g2 = sku2[lane * 5 + 2];
                    g3 = sku2[lane * 5 + 3]; g4 = sku2[lane * 5 + 4];
                }
                BFLYU(g0, g1, g2, g3, g4, NW)
                float x5 = 0.0f;
                if (lane < 5) {
                    ull key = (lane == 0) ? g0 : (lane == 1) ? g1 : (lane == 2) ? g2
                             : (lane == 3) ? g3 : g4;
                    if (key != ~0ull) x5 = X[(unsigned)(key & 0xFFFFFFFFull)];
                }
                float x0 = __shfl(x5, 0, 64), x1 = __shfl(x5, 1, 64), x2 = __shfl(x5, 2, 64),
                      x3 = __shfl(x5, 3, 64), x4v = __shfl(x5, 4, 64);
                if (lane == 0) {
                    float s = x0; s += x1; s += x2; s += x3; s += x4v;
                    v_sh = s * 0.2f;
                }
            }
            __syncthreads();
            v = v_sh;
            __syncthreads();
        }
    }

    // write the missing bytes (disjoint from producers' observed bytes)
    for (int m = tid; m < n_miss; m += TPB) out[miss_idx[m]] = v;
}

// Exact single-block fallback if ws is unusable or shapes don't fit the scheme.
__global__ void __launch_bounds__(1024) knn_exact_kernel(
    const float* __restrict__ X, const int* __restrict__ miss_idx,
    const int* __restrict__ obs_idx, float* __restrict__ out,
    int n, int n_obs, int n_miss)
{
    __shared__ ull   sku[(1024 / 64) * 5];
    __shared__ float v_sh;
    const int tid = threadIdx.x, wid = tid >> 6, lane = tid & 63;
    const int n4 = n >> 2;
    for (int i = tid; i < n4; i += 1024)
        reinterpret_cast<float4*>(out)[i] = reinterpret_cast<const float4*>(X)[i];
    for (int t = (n4 << 2) + tid; t < n; t += 1024) out[t] = X[t];

    float v = 0.0f;
    for (int it = 0; it < 3; ++it) {
        ull k0 = ~0ull, k1 = ~0ull, k2 = ~0ull, k3 = ~0ull, k4 = ~0ull;
        for (int e = tid; e < n_obs; e += 1024) {
            int p = obs_idx[e];
            float df = v - X[p];
            insert5u(((ull)__float_as_uint(df * df) << 32) | (unsigned)p, k0, k1, k2, k3, k4);
        }
        BFLYU(k0, k1, k2, k3, k4, 64)
        if (lane == 0) {
            sku[wid * 5 + 0] = k0; sku[wid * 5 + 1] = k1; sku[wid * 5 + 2] = k2;
            sku[wid * 5 + 3] = k3; sku[wid * 5 + 4] = k4;
        }
        __syncthreads();
        if (wid == 0) {
            ull g0 = ~0ull, g1 = ~0ull, g2 = ~0ull, g3 = ~0ull, g4 = ~0ull;
            if (lane < 16) {
                g0 = sku[lane * 5 + 0]; g1 = sku[lane * 5 + 1]; g2 = sku[lane * 5 + 2];
                g3 = sku[lane * 5 + 3]; g4 = sku[lane * 5 + 4];
            }
            BFLYU(g0, g1, g2, g3, g4, 16)
            float x5 = 0.0f;
            if (lane < 5) {
                ull key = (lane == 0) ? g0 : (lane == 1) ? g1 : (lane == 2) ? g2
                         : (lane == 3) ? g3 : g4;
                if (key != ~0ull) x5 = X[(unsigned)(key & 0xFFFFFFFFull)];
            }
            float x0 = __shfl(x5, 0, 64), x1 = __shfl(x5, 1, 64), x2 = __shfl(x5, 2, 64),
                  x3 = __shfl(x5, 3, 64), x4v = __shfl(x5, 4, 64);
            if (lane == 0) { float s = x0; s += x1; s += x2; s += x3; s += x4v; v_sh = s * 0.2f; }
        }
        __syncthreads();
        v = v_sh;
        __syncthreads();
    }
    for (int m = tid; m < n_miss; m += 1024) out[miss_idx[m]] = v;
}

extern "C" void kernel_launch(void* const* d_in, const int* in_sizes, int n_in,
                              void* d_out, int out_size, void* d_ws, size_t ws_size,
                              hipStream_t stream) {
    const float* X        = (const float*)d_in[0];
    const int*   miss_idx = (const int*)d_in[1];
    const int*   obs_idx  = (const int*)d_in[2];
    float*       out      = (float*)d_out;

    int n_miss = in_sizes[1];
    int n_obs  = in_sizes[2];
    int n      = out_size;
    int per    = (n_obs + NPROD - 1) / NPROD;
    int n4     = n >> 2;
    int epb4   = (n4 + NPROD - 1) / NPROD;

    // ws layout: flags[32] @0 | counts[32] @256 | cand (ull) @4096
    size_t need = 4096 + (size_t)NPROD * PERCAP * sizeof(ull);
    bool fits = (ws_size >= need) && (per <= 4 * TPB) &&
                ((epb4 * 4 + 32) <= BMW * 32) && (n_miss > 0);
    if (!fits) {
        knn_exact_kernel<<<1, 1024, 0, stream>>>(X, miss_idx, obs_idx, out,
                                                 n, n_obs, n_miss);
        return;
    }

    int  percap = PERCAP;
    int* flags  = (int*)d_ws;
    int* counts = (int*)((char*)d_ws + 256);
    ull* cand   = (ull*)((char*)d_ws + 4096);

    knn_fused_kernel<<<NPROD + 1, TPB, 0, stream>>>(X, miss_idx, obs_idx, out,
                                                    flags, counts, cand,
                                                    n, n_obs, n_miss, per, percap);
}

// Round 10
// 26.845 us; speedup vs baseline: 1.2238x; 1.2238x over previous
//
#include <hip/hip_runtime.h>
#include <math.h>

#define ATPB 256          // prep threads/block
#define ABLK 32           // prep blocks
#define BTPB 512          // solve threads (1 block)
#define CAP_LDS 2048      // max total candidates staged in solve LDS
#define PERCAP 256        // candidate slots per prep block (expected ~40 used)

typedef unsigned long long ull;

__device__ __forceinline__ ull umin64(ull a, ull b) { return a < b ? a : b; }
__device__ __forceinline__ ull umax64(ull a, ull b) { return a > b ? a : b; }

// Branchless order-statistic merge of two sorted 5-lists (ascending).
// Keys are unique -> total order; low tie-break bits = candidate order =
// original-index order, exactly matching jax.lax.top_k semantics.
__device__ __forceinline__ void merge5(ull& a0, ull& a1, ull& a2, ull& a3, ull& a4,
                                       ull b0, ull b1, ull b2, ull b3, ull b4) {
    ull m0 = umin64(a0, b0);
    ull m1 = umin64(umin64(a1, b1), umax64(a0, b0));
    ull m2 = umin64(umin64(a2, b2), umin64(umax64(a0, b1), umax64(a1, b0)));
    ull m3 = umin64(umin64(a3, b3),
                    umin64(umin64(umax64(a0, b2), umax64(a1, b1)), umax64(a2, b0)));
    ull m4 = umin64(umin64(a4, b4),
                    umin64(umin64(umax64(a0, b3), umax64(a1, b2)),
                           umin64(umax64(a2, b1), umax64(a3, b0))));
    a0 = m0; a1 = m1; a2 = m2; a3 = m3; a4 = m4;
}

__device__ __forceinline__ void insert5(ull key, ull& k0, ull& k1, ull& k2, ull& k3, ull& k4) {
    if (key < k4) {
        k4 = key;
        ull t;
        if (k4 < k3) { t = k3; k3 = k4; k4 = t; }
        if (k3 < k2) { t = k2; k2 = k3; k3 = t; }
        if (k2 < k1) { t = k1; k1 = k2; k2 = t; }
        if (k1 < k0) { t = k0; k0 = k1; k1 = t; }
    }
}

#define BUTTERFLY(kk0,kk1,kk2,kk3,kk4,WIDTH)                        \
    for (int mask_ = 1; mask_ < (WIDTH); mask_ <<= 1) {             \
        ull b0_ = __shfl_xor(kk0, mask_, 64);                       \
        ull b1_ = __shfl_xor(kk1, mask_, 64);                       \
        ull b2_ = __shfl_xor(kk2, mask_, 64);                       \
        ull b3_ = __shfl_xor(kk3, mask_, 64);                       \
        ull b4_ = __shfl_xor(kk4, mask_, 64);                       \
        merge5(kk0, kk1, kk2, kk3, kk4, b0_, b1_, b2_, b3_, b4_);   \
    }

// ---------------------------------------------------------------------------
// Kernel A: copy X->out + build candidate set (per-block regions, no atomics,
// no initialization required: counts[b] is overwritten unconditionally).
// Bound proof (v0=0): r0 = global 5th-smallest |x|. |v1|<=r0, d5(v1)<=2r0 ->
// 5NN(v1) within |x|<=3r0; |v2|<=3r0, d5(v2)<=4r0 -> 5NN(v2) within |x|<=7r0.
// Block filter keeps |x| <= 8*r_loc, r_loc >= r0 -> guaranteed superset.
// ---------------------------------------------------------------------------
__global__ void __launch_bounds__(ATPB) knn_prep_kernel(
    const float* __restrict__ X, const int* __restrict__ obs_idx,
    float* __restrict__ out, uint2* __restrict__ cand, int* __restrict__ counts,
    int n, int n_obs, int per, int percap)
{
    const int tid  = threadIdx.x;
    const int b    = blockIdx.x;
    const int gtid = b * ATPB + tid;
    const int gsz  = ABLK * ATPB;

    // ---- copy X -> out (float4 + tail) ----
    const int n4 = n >> 2;
    for (int i = gtid; i < n4; i += gsz)
        reinterpret_cast<float4*>(out)[i] = reinterpret_cast<const float4*>(X)[i];
    for (int t = (n4 << 2) + gtid; t < n; t += gsz) out[t] = X[t];

    // ---- this block's contiguous slice of observed values ----
    const int j0 = b * per;
    const int j1 = min(j0 + per, n_obs);

    int   oj[4];
    float xv[4];
#pragma unroll
    for (int u = 0; u < 4; ++u) {
        int j = j0 + tid + u * ATPB;
        oj[u] = (j < j1) ? obs_idx[j] : 0;
    }
#pragma unroll
    for (int u = 0; u < 4; ++u) xv[u] = X[oj[u]];

    // ---- local top-5 by x^2 (distance to 0) ----
    ull k0 = ~0ull, k1 = ~0ull, k2 = ~0ull, k3 = ~0ull, k4 = ~0ull;
#pragma unroll
    for (int u = 0; u < 4; ++u) {
        int j = j0 + tid + u * ATPB;
        if (j < j1) {
            float d = xv[u] * xv[u];
            insert5(((ull)__float_as_uint(d) << 32) | (unsigned)j, k0, k1, k2, k3, k4);
        }
    }
    BUTTERFLY(k0, k1, k2, k3, k4, 64)

    __shared__ ull   sk[(ATPB / 64) * 5];
    __shared__ float thr_sh;
    __shared__ int   wcnt[ATPB / 64];
    const int wid = tid >> 6, lane = tid & 63;
    if (lane == 0) {
        sk[wid * 5 + 0] = k0; sk[wid * 5 + 1] = k1; sk[wid * 5 + 2] = k2;
        sk[wid * 5 + 3] = k3; sk[wid * 5 + 4] = k4;
    }
    __syncthreads();
    if (wid == 0) {
        ull g0 = ~0ull, g1 = ~0ull, g2 = ~0ull, g3 = ~0ull, g4 = ~0ull;
        if (lane < ATPB / 64) {
            g0 = sk[lane * 5 + 0]; g1 = sk[lane * 5 + 1]; g2 = sk[lane * 5 + 2];
            g3 = sk[lane * 5 + 3]; g4 = sk[lane * 5 + 4];
        }
        BUTTERFLY(g0, g1, g2, g3, g4, ATPB / 64)
        if (lane == 0) {
            float d5 = __uint_as_float((unsigned)(g4 >> 32));   // r_loc^2
            thr_sh = (d5 < INFINITY) ? 64.0f * d5 : INFINITY;   // (8*r_loc)^2
        }
    }
    __syncthreads();
    const float thr = thr_sh;
    const ull lanemask_lt = (1ull << lane) - 1ull;

    // ---- order-preserving compaction into this block's region ----
    int base = 0;
#pragma unroll
    for (int u = 0; u < 4; ++u) {
        int  j    = j0 + tid + u * ATPB;
        bool keep = (j < j1) && (xv[u] * xv[u] <= thr);
        ull  mask = __ballot(keep);
        if (lane == 0) wcnt[wid] = (int)__popcll(mask);
        __syncthreads();
        int wbase = 0, utotal = 0;
#pragma unroll
        for (int w = 0; w < ATPB / 64; ++w) {
            if (w == wid) wbase = utotal;
            utotal += wcnt[w];
        }
        int pos = base + wbase + (int)__popcll(mask & lanemask_lt);
        if (keep && pos < percap)
            cand[b * percap + pos] = make_uint2(__float_as_uint(xv[u]), (unsigned)j);
        base += utotal;
        __syncthreads();
    }
    if (tid == 0 && percap >= 0) counts[b] = base;   // may exceed percap -> fallback
}

// ---------------------------------------------------------------------------
// Kernel B (1 block): 3 exact fixed-point iterations over the candidates,
// then scatter. Winner values resolved by register/LDS match (no global loads).
// ---------------------------------------------------------------------------
__global__ void __launch_bounds__(BTPB) knn_solve_kernel(
    const float* __restrict__ X, const int* __restrict__ miss_idx,
    const int* __restrict__ obs_idx, const uint2* __restrict__ cand,
    const int* __restrict__ counts, float* __restrict__ out,
    int n_obs, int n_miss, int percap)
{
    __shared__ uint2 cs[CAP_LDS];
    __shared__ int   carr[ABLK];
    __shared__ ull   sk[(BTPB / 64) * 5];
    __shared__ ull   wk[5];
    __shared__ float vals[5];
    __shared__ float v_sh;

    const int tid = threadIdx.x, wid = tid >> 6, lane = tid & 63;

    if (tid < ABLK) carr[tid] = (percap > 0) ? counts[tid] : (percap <= 0 ? 0x7FFFFFFF : 0);
    __syncthreads();

    // every thread derives: total C, its staging base, overflow flag
    int C = 0, bad = (percap <= 0);
    const int myb = tid >> 4;                 // 16 staging threads per region
    int mybase = 0;
#pragma unroll
    for (int b2 = 0; b2 < ABLK; ++b2) {
        int c2 = carr[b2];
        if (b2 == myb) mybase = C;
        C += c2;
        if (c2 > percap) bad = 1;
    }
    const bool usec = !bad && (C >= 5) && (C <= CAP_LDS);

    if (usec) {
        const int cb = carr[myb];
        for (int e = (tid & 15); e < cb; e += 16)
            cs[mybase + e] = cand[myb * percap + e];
    }
    __syncthreads();

    float v = 0.0f;  // reference inits missing entries to 0

    if (usec) {
        // cache candidate values in registers (slot order == original-j order)
        float cx[4];
#pragma unroll
        for (int k = 0; k < 4; ++k) {
            int e = tid + k * BTPB;
            cx[k] = (e < C) ? __uint_as_float(cs[e].x) : 0.0f;
        }

        for (int it = 0; it < 3; ++it) {
            ull k0 = ~0ull, k1 = ~0ull, k2 = ~0ull, k3 = ~0ull, k4 = ~0ull;
#pragma unroll
            for (int k = 0; k < 4; ++k) {
                int e = tid + k * BTPB;
                if (e < C) {
                    float diff = v - cx[k];
                    float d = diff * diff;
                    // slot index e: same total order & tie-break as original j
                    insert5(((ull)__float_as_uint(d) << 32) | (unsigned)e,
                            k0, k1, k2, k3, k4);
                }
            }
            BUTTERFLY(k0, k1, k2, k3, k4, 64)
            if (lane == 0) {
                sk[wid * 5 + 0] = k0; sk[wid * 5 + 1] = k1; sk[wid * 5 + 2] = k2;
                sk[wid * 5 + 3] = k3; sk[wid * 5 + 4] = k4;
            }
            __syncthreads();
            if (wid == 0) {
                ull g0 = ~0ull, g1 = ~0ull, g2 = ~0ull, g3 = ~0ull, g4 = ~0ull;
                if (lane < BTPB / 64) {
                    g0 = sk[lane * 5 + 0]; g1 = sk[lane * 5 + 1]; g2 = sk[lane * 5 + 2];
                    g3 = sk[lane * 5 + 3]; g4 = sk[lane * 5 + 4];
                }
                BUTTERFLY(g0, g1, g2, g3, g4, BTPB / 64)
                if (lane == 0) {
                    wk[0] = g0; wk[1] = g1; wk[2] = g2; wk[3] = g3; wk[4] = g4;
                }
            }
            __syncthreads();
            // winner-value match from register cache (unique slots -> no race)
            int wj0 = (int)(unsigned)(wk[0] & 0xFFFFFFFFull);
            int wj1 = (int)(unsigned)(wk[1] & 0xFFFFFFFFull);
            int wj2 = (int)(unsigned)(wk[2] & 0xFFFFFFFFull);
            int wj3 = (int)(unsigned)(wk[3] & 0xFFFFFFFFull);
            int wj4 = (int)(unsigned)(wk[4] & 0xFFFFFFFFull);
#pragma unroll
            for (int k = 0; k < 4; ++k) {
                int e = tid + k * BTPB;
                if (e < C) {
                    if (e == wj0) vals[0] = cx[k];
                    if (e == wj1) vals[1] = cx[k];
                    if (e == wj2) vals[2] = cx[k];
                    if (e == wj3) vals[3] = cx[k];
                    if (e == wj4) vals[4] = cx[k];
                }
            }
            __syncthreads();
            if (tid == 0) {
                // ascending (dist, idx) order — matches reference sum order
                float s = vals[0]; s += vals[1]; s += vals[2]; s += vals[3]; s += vals[4];
                v_sh = s * 0.2f;
            }
            __syncthreads();
            v = v_sh;
            __syncthreads();
        }
    } else {
        // exact full-scan fallback (never expected to trigger)
        for (int it = 0; it < 3; ++it) {
            ull k0 = ~0ull, k1 = ~0ull, k2 = ~0ull, k3 = ~0ull, k4 = ~0ull;
            for (int e = tid; e < n_obs; e += BTPB) {
                float x = X[obs_idx[e]];
                float diff = v - x;
                float d = diff * diff;
                insert5(((ull)__float_as_uint(d) << 32) | (unsigned)e, k0, k1, k2, k3, k4);
            }
            BUTTERFLY(k0, k1, k2, k3, k4, 64)
            if (lane == 0) {
                sk[wid * 5 + 0] = k0; sk[wid * 5 + 1] = k1; sk[wid * 5 + 2] = k2;
                sk[wid * 5 + 3] = k3; sk[wid * 5 + 4] = k4;
            }
            __syncthreads();
            if (wid == 0) {
                ull g0 = ~0ull, g1 = ~0ull, g2 = ~0ull, g3 = ~0ull, g4 = ~0ull;
                if (lane < BTPB / 64) {
                    g0 = sk[lane * 5 + 0]; g1 = sk[lane * 5 + 1]; g2 = sk[lane * 5 + 2];
                    g3 = sk[lane * 5 + 3]; g4 = sk[lane * 5 + 4];
                }
                BUTTERFLY(g0, g1, g2, g3, g4, BTPB / 64)
                ull h0 = __shfl(g0, 0, 64), h1 = __shfl(g1, 0, 64), h2 = __shfl(g2, 0, 64),
                    h3 = __shfl(g3, 0, 64), h4 = __shfl(g4, 0, 64);
                float xx = 0.0f;
                if (lane < 5) {
                    ull key = (lane == 0) ? h0 : (lane == 1) ? h1 : (lane == 2) ? h2
                             : (lane == 3) ? h3 : h4;
                    int jj = (int)(unsigned)(key & 0xFFFFFFFFull);
                    xx = X[obs_idx[jj]];
                }
                float x0 = __shfl(xx, 0, 64), x1 = __shfl(xx, 1, 64), x2 = __shfl(xx, 2, 64),
                      x3 = __shfl(xx, 3, 64), x4 = __shfl(xx, 4, 64);
                if (lane == 0) {
                    float s = x0; s += x1; s += x2; s += x3; s += x4;
                    v_sh = s * 0.2f;
                }
            }
            __syncthreads();
            v = v_sh;
            __syncthreads();
        }
    }

    // scatter the single imputed value
    for (int m = tid; m < n_miss; m += BTPB) out[miss_idx[m]] = v;
}

extern "C" void kernel_launch(void* const* d_in, const int* in_sizes, int n_in,
                              void* d_out, int out_size, void* d_ws, size_t ws_size,
                              hipStream_t stream) {
    const float* X        = (const float*)d_in[0];
    const int*   miss_idx = (const int*)d_in[1];
    const int*   obs_idx  = (const int*)d_in[2];
    float*       out      = (float*)d_out;

    const int n_miss = in_sizes[1];
    const int n_obs  = in_sizes[2];
    const int n      = out_size;
    const int per    = (n_obs + ABLK - 1) / ABLK;

    // ws layout: counts[32] at 0 (256B-aligned region), cand[] at 256.
    int percap = PERCAP;
    size_t need = 256 + (size_t)ABLK * PERCAP * sizeof(uint2);
    if (ws_size < need) {
        if (ws_size >= 512)
            percap = (int)((ws_size - 256) / (ABLK * sizeof(uint2)));
        else
            percap = -1;   // no usable ws: force exact fallback
    }
    int*   counts = (int*)d_ws;
    uint2* cand   = (uint2*)((char*)d_ws + 256);

    knn_prep_kernel<<<ABLK, ATPB, 0, stream>>>(X, obs_idx, out, cand, counts,
                                               n, n_obs, per, percap);
    knn_solve_kernel<<<1, BTPB, 0, stream>>>(X, miss_idx, obs_idx, cand, counts,
                                             out, n_obs, n_miss, percap);
}